// Round 12
// baseline (3283.413 us; speedup 1.0000x reference)
//
#include <hip/hip_runtime.h>

// Dims fixed by the reference
#define LAY 2
#define BATCH 64
#define TMAX 512
#define DIM 256
#define AST 264   // LDS activation row stride (bytes, fp8)

typedef float floatx4 __attribute__((ext_vector_type(4)));
typedef _Float16 halfx8 __attribute__((ext_vector_type(8)));
#define MFMA_FP8 __builtin_amdgcn_mfma_f32_16x16x32_fp8_fp8
#define MFMA_F16 __builtin_amdgcn_mfma_f32_16x16x32_f16
#define PIN(x) asm volatile("" : "+v"(x))

// d_ws layout (requires ws >= ~74 MB)
#define OFF_WPW 0x60000     // f16 B-frag W-mats, 6 x 128 KB
#define OFF_XP  0x200000    // layer-0 X-projections fp8, 25.2 MB
#define OFF_HP  0x1C00000   // layer-1 input projections fp8, 25.2 MB
#define OFF_HN  0x3600000   // hn0 f16 [b*512+t][256], 16.8 MB

__device__ __forceinline__ unsigned int pk2(float a, float b) {
    return (unsigned int)__builtin_amdgcn_cvt_pk_fp8_f32(a, b, 0, false);  // OCP e4m3 x2
}
__device__ __forceinline__ unsigned int pkh(float a, float b) {  // 2xf32 -> packed f16 (RTZ)
    union { decltype(__builtin_amdgcn_cvt_pkrtz(0.f, 0.f)) h; unsigned int u; } cv;
    cv.h = __builtin_amdgcn_cvt_pkrtz(a, b);
    return cv.u;
}
__device__ __forceinline__ void unp4(unsigned int u, float* f) {
    auto lo = __builtin_amdgcn_cvt_pk_f32_fp8((int)u, false);
    auto hi = __builtin_amdgcn_cvt_pk_f32_fp8((int)u, true);
    f[0] = lo[0]; f[1] = lo[1]; f[2] = hi[0]; f[3] = hi[1];
}
__device__ __forceinline__ float sigf(float x) { return 1.f / (1.f + __expf(-x)); }
__device__ __forceinline__ float tanhfast2y(float twoy) { return 2.f * sigf(twoy) - 1.f; }

// ---------------------------------------------------------------------------
// Weight prep. U-mats fp8 e4m3 x8 (identical layout to R8-R10).
// W-mats now f16 (same fragment geometry; pkrtz pack):
//   byte ((mw*16+nt)*8+kf)*1024 + lane*16 + 2j -> f16 W[k=kf*32+(lane>>4)*8+j][n=nt*16+(lane&15)]
// Also zeroes d_out.
// ---------------------------------------------------------------------------
__global__ void prep_weights(const float* __restrict__ Wz, const float* __restrict__ Wr,
                             const float* __restrict__ Wh, const float* __restrict__ Uz,
                             const float* __restrict__ Ur, const float* __restrict__ Uh,
                             unsigned char* __restrict__ ws, float* __restrict__ out) {
    int T = blockIdx.x * 256 + threadIdx.x;  // 1536*256 = 393216
    if (T == 0) out[0] = 0.f;
    if (T < 196608) {  // U-mats, fp8
        int e = T & 3, half = (T >> 2) & 1, lane = (T >> 3) & 63;
        int kp = (T >> 9) & 3, nt = (T >> 11) & 15, mu = T >> 15;
        int g = mu % 3, l = mu / 3;
        const float* s = (g == 0 ? Uz : g == 1 ? Ur : Uh) + l * 65536;
        int n  = nt * 16 + (lane & 15);
        int k0 = (2 * kp + half) * 32 + (lane >> 4) * 8 + 2 * e;
        float w0 = s[(k0 << 8) + n] * 8.f;        // x8: dodge e4m3 denormals
        float w1 = s[((k0 + 1) << 8) + n] * 8.f;  // undone by 0.125 post-acc
        int addr = ((mu * 16 + nt) * 4 + kp) * 1024 + lane * 16 + half * 8 + 2 * e;
        *(unsigned short*)(ws + addr) = (unsigned short)(pk2(w0, w1) & 0xffff);
    } else {           // W-mats, f16
        int T2 = T - 196608;
        int e = T2 & 3, lane = (T2 >> 2) & 63;
        int kf = (T2 >> 8) & 7, nt = (T2 >> 11) & 15, mw = T2 >> 15;
        int g = mw % 3, l = mw / 3;
        const float* s = (g == 0 ? Wz : g == 1 ? Wr : Wh) + l * 65536;
        int n  = nt * 16 + (lane & 15);
        int k0 = kf * 32 + (lane >> 4) * 8 + 2 * e;
        unsigned int v = pkh(s[(k0 << 8) + n], s[((k0 + 1) << 8) + n]);
        int addr = ((mw * 16 + nt) * 8 + kf) * 1024 + lane * 16 + 4 * e;
        *(unsigned int*)(ws + OFF_WPW + addr) = v;
    }
}

// ---------------------------------------------------------------------------
// Projection GEMM, TRANSPOSED (A=W-frag, B=act-frag -> lane owns 1 batch row x
// 4 consecutive out-cols). Grid 2048 = bg*512+t; wave = 16-col tile.
// Output fp8(x16): xp[(bgt*48 + g*16 + w)*64 + lane] = cols quad*4..+3 of row l15.
// ---------------------------------------------------------------------------
template <int F32SRC>
__global__ __launch_bounds__(1024) void proj_kernel(const void* __restrict__ src,
                                                    const unsigned char* __restrict__ wpW,
                                                    unsigned int* __restrict__ xpo, int matbase) {
    const int bgt = blockIdx.x;
    const int t = bgt & 511, bg = bgt >> 9;
    const int tid = threadIdx.x, wave = tid >> 6, lane = tid & 63;
    const int l15 = lane & 15, quad = lane >> 4;
    const size_t rowoff = ((size_t)(bg * 16 + l15) * 512 + t) * 256;

    halfx8 af[8];  // activation rows (B-operand of the transposed matmul)
    if (F32SRC) {
        const float* s = (const float*)src + rowoff;
#pragma unroll
        for (int kf = 0; kf < 8; ++kf) {
            float4 a = *(const float4*)(s + kf * 32 + quad * 8);
            float4 b = *(const float4*)(s + kf * 32 + quad * 8 + 4);
            union { unsigned int u[4]; halfx8 v; } cv;
            cv.u[0] = pkh(a.x, a.y); cv.u[1] = pkh(a.z, a.w);
            cv.u[2] = pkh(b.x, b.y); cv.u[3] = pkh(b.z, b.w);
            af[kf] = cv.v;
        }
    } else {
        const _Float16* s = (const _Float16*)src + rowoff;
#pragma unroll
        for (int kf = 0; kf < 8; ++kf) af[kf] = *(const halfx8*)(s + kf * 32 + quad * 8);
    }

    floatx4 az = {0.f, 0.f, 0.f, 0.f}, ar = az, ah = az;
    const unsigned char* bz = wpW + (size_t)(((matbase + 0) * 16 + wave) * 8) * 1024 + lane * 16;
    const unsigned char* br = wpW + (size_t)(((matbase + 1) * 16 + wave) * 8) * 1024 + lane * 16;
    const unsigned char* bh = wpW + (size_t)(((matbase + 2) * 16 + wave) * 8) * 1024 + lane * 16;
#pragma unroll
    for (int kf = 0; kf < 8; ++kf) {  // A = W-frag, B = act-frag  (transposed)
        az = MFMA_F16(*(const halfx8*)(bz + kf * 1024), af[kf], az, 0, 0, 0);
        ar = MFMA_F16(*(const halfx8*)(br + kf * 1024), af[kf], ar, 0, 0, 0);
        ah = MFMA_F16(*(const halfx8*)(bh + kf * 1024), af[kf], ah, 0, 0, 0);
    }
    const size_t ob = (size_t)bgt * 3072 + wave * 64 + lane;
    xpo[ob]        = pk2(16.f * az[0], 16.f * az[1]) | (pk2(16.f * az[2], 16.f * az[3]) << 16);
    xpo[ob + 1024] = pk2(16.f * ar[0], 16.f * ar[1]) | (pk2(16.f * ar[2], 16.f * ar[3]) << 16);
    xpo[ob + 2048] = pk2(16.f * ah[0], 16.f * ah[1]) | (pk2(16.f * ah[2], 16.f * ah[3]) << 16);
}

// ---------------------------------------------------------------------------
// Recurrence, TRANSPOSED: lane owns row l15 x cols nt*16+quad*4..+3. All LDS
// epilogue traffic is packed b32/b128. XP register-prefetched one step ahead.
// ---------------------------------------------------------------------------
template <int SCORE>
__global__ __launch_bounds__(1024, 4) void recur_kernel(const unsigned int* __restrict__ xp,
                                                        const unsigned char* __restrict__ wpU,
                                                        int lbase,
                                                        unsigned short* __restrict__ hnout,
                                                        const int* __restrict__ xlen,
                                                        const float* __restrict__ xlab,
                                                        const float* __restrict__ Wo,
                                                        float* __restrict__ out) {
    __shared__ __align__(16) unsigned char s1q[16][AST];
    __shared__ __align__(16) unsigned char rsq[16][AST];
    __shared__ __align__(16) float s1o[16][264];
    __shared__ float wo1s[DIM];

    const int tid = threadIdx.x, wave = tid >> 6, lane = tid & 63;
    const int l15 = lane & 15, quad = lane >> 4;
    const int bg = blockIdx.x, b0 = bg * 16;

    for (int i = tid; i < 16 * AST; i += 1024) ((unsigned char*)s1q)[i] = 0;
    if (SCORE && tid < DIM) wo1s[tid] = Wo[2 * tid + 1];
    const int lenw = SCORE ? xlen[b0 + wave] : 0;
    const float labw = SCORE ? xlab[b0 + wave] : 0.f;
    int v = xlen[b0 + l15];
#pragma unroll
    for (int o = 1; o < 16; o <<= 1) v = max(v, __shfl_xor(v, o));
    const int tmax = __builtin_amdgcn_readfirstlane(v);

    const int nt = wave;
    const int colb = nt * 16 + quad * 4;   // this lane's 4 consecutive cols (row l15)

    long uz[8], ur[8], uh[8];
    {
        const unsigned char* pz = wpU + (size_t)(((lbase + 0) * 16 + nt) * 4) * 1024 + lane * 16;
        const unsigned char* pr = wpU + (size_t)(((lbase + 1) * 16 + nt) * 4) * 1024 + lane * 16;
        const unsigned char* ph = wpU + (size_t)(((lbase + 2) * 16 + nt) * 4) * 1024 + lane * 16;
#pragma unroll
        for (int kf = 0; kf < 8; ++kf) {
            int o = (kf >> 1) * 1024 + (kf & 1) * 8;
            uz[kf] = *(const long*)(pz + o);
            ur[kf] = *(const long*)(pr + o);
            uh[kf] = *(const long*)(ph + o);
        }
#pragma unroll
        for (int kf = 0; kf < 8; ++kf) { PIN(uz[kf]); PIN(ur[kf]); PIN(uh[kf]); }
    }
    float s1r[4] = {};   // S1[row=l15][colb+i], register-resident
    float accl = 0.f;
    __syncthreads();

    float4 wo1r;
    if (SCORE) wo1r = *(const float4*)&wo1s[lane * 4];

    // XP: depth-1 register prefetch (one full step of latency cover)
    const unsigned int* xptr = xp + (size_t)bg * 512 * 3072 + nt * 64 + lane;
    unsigned int xzc = xptr[0], xrc = xptr[1024], xhc = xptr[2048];

    for (int t = 0; t < tmax; ++t) {
        const unsigned int* xn = xptr + 3072;
        unsigned int xzn = 0, xrn = 0, xhn = 0;
        if (t + 1 < tmax) { xzn = xn[0]; xrn = xn[1024]; xhn = xn[2048]; }

        // ---- phase 1: r (critical path) + z-MFMAs; A=U-frag, B=S-frag ----
        long sf[8];
#pragma unroll
        for (int kf = 0; kf < 8; ++kf) sf[kf] = *(const long*)&s1q[l15][kf * 32 + quad * 8];
        floatx4 za = {0.f, 0.f, 0.f, 0.f}, ra = za;
#pragma unroll
        for (int kf = 0; kf < 8; ++kf) {
            ra = MFMA_FP8(ur[kf], sf[kf], ra, 0, 0, 0);
            za = MFMA_FP8(uz[kf], sf[kf], za, 0, 0, 0);
        }
        float xrf[4];
        unp4(xrc, xrf);
        float rs[4];
#pragma unroll
        for (int i = 0; i < 4; ++i)
            rs[i] = sigf(0.125f * ra[i] + 0.0625f * xrf[i]) * s1r[i];
        *(unsigned int*)&rsq[l15][colb] = pk2(rs[0], rs[1]) | (pk2(rs[2], rs[3]) << 16);
        __syncthreads();

        // ---- phase 2: h; z-sigmoid overlaps the Uh MFMA ----
        long rf[8];
#pragma unroll
        for (int kf = 0; kf < 8; ++kf) rf[kf] = *(const long*)&rsq[l15][kf * 32 + quad * 8];
        floatx4 ha = {0.f, 0.f, 0.f, 0.f};
#pragma unroll
        for (int kf = 0; kf < 8; ++kf) ha = MFMA_FP8(uh[kf], rf[kf], ha, 0, 0, 0);
        float xzf[4], xhf[4];
        unp4(xzc, xzf); unp4(xhc, xhf);
        float hn[4];
#pragma unroll
        for (int i = 0; i < 4; ++i) {
            float z = sigf(0.125f * za[i] + 0.0625f * xzf[i]);
            float h = tanhfast2y(0.25f * ha[i] + 0.125f * xhf[i]);
            hn[i] = (1.f - z) * s1r[i] + z * h;
            s1r[i] = hn[i];
        }
        *(unsigned int*)&s1q[l15][colb] = pk2(hn[0], hn[1]) | (pk2(hn[2], hn[3]) << 16);
        if (SCORE) *(float4*)&s1o[l15][colb] = make_float4(hn[0], hn[1], hn[2], hn[3]);
        __syncthreads();

        if (!SCORE) {
            // direct hn0 emit from registers: one 8B f16 store per lane
            uint2 o2; o2.x = pkh(hn[0], hn[1]); o2.y = pkh(hn[2], hn[3]);
            *(uint2*)(hnout + ((size_t)(b0 + l15) * 512 + t) * 256 + colb) = o2;
        } else {
            // distributed score: wave w scores row w
            float4 sv = *(const float4*)&s1o[wave][lane * 4];
            float p = sv.x * wo1r.x;
            p = fmaf(sv.y, wo1r.y, p);
            p = fmaf(sv.z, wo1r.z, p);
            p = fmaf(sv.w, wo1r.w, p);
            p += __shfl_xor(p, 1);  p += __shfl_xor(p, 2);  p += __shfl_xor(p, 4);
            p += __shfl_xor(p, 8);  p += __shfl_xor(p, 16); p += __shfl_xor(p, 32);
            if (lane == 0 && t < lenw) {
                float sc = sigf(p);
                float d = labw - sc;
                accl = fmaf(d, d, accl);
            }
        }
        xzc = xzn; xrc = xrn; xhc = xhn; xptr = xn;
    }

    if (SCORE && lane == 0) atomicAdd(out, accl);
}

extern "C" void kernel_launch(void* const* d_in, const int* in_sizes, int n_in,
                              void* d_out, int out_size, void* d_ws, size_t ws_size,
                              hipStream_t stream) {
    const float* x    = (const float*)d_in[0];
    const int*   xlen = (const int*)d_in[1];
    const float* xlab = (const float*)d_in[2];
    const float* Wz   = (const float*)d_in[3];
    const float* Uz   = (const float*)d_in[4];
    const float* Wr   = (const float*)d_in[5];
    const float* Ur   = (const float*)d_in[6];
    const float* Wh   = (const float*)d_in[7];
    const float* Uh   = (const float*)d_in[8];
    const float* Wo   = (const float*)d_in[9];
    float* out = (float*)d_out;

    unsigned char* ws  = (unsigned char*)d_ws;
    unsigned char* wpU = ws;                                 // fp8 U-frags, 384 KB
    unsigned char* wpW = ws + OFF_WPW;                       // f16 W-frags, 768 KB
    unsigned int*  XP  = (unsigned int*)(ws + OFF_XP);       // 25.2 MB
    unsigned int*  HP  = (unsigned int*)(ws + OFF_HP);       // 25.2 MB
    unsigned short* HN = (unsigned short*)(ws + OFF_HN);     // f16 hn0, 16.8 MB

    // ws re-poisoned every call -> rebuild everything each time.
    prep_weights<<<1536, 256, 0, stream>>>(Wz, Wr, Wh, Uz, Ur, Uh, ws, out);
    proj_kernel<1><<<2048, 1024, 0, stream>>>(x, wpW, XP, 0);                         // A: x @ W(l0)
    recur_kernel<0><<<4, 1024, 0, stream>>>(XP, wpU, 0, HN, xlen, xlab, Wo, out);     // B: layer-0 scan
    proj_kernel<0><<<2048, 1024, 0, stream>>>(HN, wpW, HP, 3);                        // C: hn0 @ W(l1)
    recur_kernel<1><<<4, 1024, 0, stream>>>(HP, wpU, 3, nullptr, xlen, xlab, Wo, out);// D: layer-1 + loss
}